// Round 3
// baseline (898.742 us; speedup 1.0000x reference)
//
#include <hip/hip_runtime.h>
#include <math.h>

#define N_NODES 20000
#define M_PAD   20096   // 157 * 128
#define N_EDGES 320000
#define DIM_IN 768
#define DIM_H 512
#define NUM_GNNS 4
#define NEG_SLOPE 0.2f

#define GEMM_TILES 628        // (M_PAD/128) * (DIM_H/128) = 157*4
#define GEMM_GRID  632        // ceil to multiple of 8 for XCD swizzle

// sliced gather kernels: 8 column slices (64 cols each), slice = bid & 7 -> XCD.
// grid 2048 blocks x 4 waves = 1024 waves/slice, 20 consecutive nodes per wave.
#define SLC_GRID 2048
#define NPW 20

typedef __attribute__((ext_vector_type(8))) short short8;
typedef __attribute__((ext_vector_type(4))) float f32x4;

#define GPTR(p) (const __attribute__((address_space(1))) void*)(p)
#define LPTR(p) (__attribute__((address_space(3))) void*)(p)

__device__ __forceinline__ float bf2f(unsigned int lo16) {
  return __uint_as_float(lo16 << 16);
}
__device__ __forceinline__ unsigned short f2bf(float f) {
  unsigned int u = __float_as_uint(f);
  u += 0x7FFFu + ((u >> 16) & 1u);   // round-to-nearest-even
  return (unsigned short)(u >> 16);
}
__device__ __forceinline__ void unpack8(uint4 v, float* f) {
  f[0] = bf2f(v.x & 0xffffu); f[1] = bf2f(v.x >> 16);
  f[2] = bf2f(v.y & 0xffffu); f[3] = bf2f(v.y >> 16);
  f[4] = bf2f(v.z & 0xffffu); f[5] = bf2f(v.z >> 16);
  f[6] = bf2f(v.w & 0xffffu); f[7] = bf2f(v.w >> 16);
}

__device__ __forceinline__ float waveReduceSum(float v) {
#pragma unroll
  for (int off = 32; off > 0; off >>= 1) v += __shfl_xor(v, off, 64);
  return v;
}
__device__ __forceinline__ float waveReduceMax(float v) {
#pragma unroll
  for (int off = 32; off > 0; off >>= 1) v = fmaxf(v, __shfl_xor(v, off, 64));
  return v;
}

// ================= MFMA GEMM (lean) + XCD tile swizzle =================
__global__ __launch_bounds__(256) void gemm_mfma_bf16(
    const unsigned short* __restrict__ A,
    const unsigned short* __restrict__ Bt,
    const float* __restrict__ bias,
    unsigned short* __restrict__ Cbf,
    int K) {
  int bid = blockIdx.x;
  int tile = (bid & 7) * (GEMM_GRID / 8) + (bid >> 3);
  if (tile >= GEMM_TILES) return;
  int brow = tile >> 2;   // 0..156
  int bcol = tile & 3;    // 0..3

  __shared__ __align__(16) unsigned short As[128 * 32];
  __shared__ __align__(16) unsigned short Bs[128 * 32];
  int tid = threadIdx.x;
  int wave = tid >> 6, lane = tid & 63;
  int wm = wave >> 1, wn = wave & 1;

  int rl = lane >> 2;
  int kc = (lane & 3) ^ ((lane >> 3) & 3);
  int r0 = 32 * wave;
  const unsigned short* gA0 = A + (size_t)(brow * 128 + r0 + rl) * K + kc * 8;
  const unsigned short* gA1 = gA0 + (size_t)16 * K;
  const unsigned short* gB0 = Bt + (size_t)(bcol * 128 + r0 + rl) * K + kc * 8;
  const unsigned short* gB1 = gB0 + (size_t)16 * K;
  unsigned short* lA0 = As + r0 * 32;
  unsigned short* lA1 = As + (r0 + 16) * 32;
  unsigned short* lB0 = Bs + r0 * 32;
  unsigned short* lB1 = Bs + (r0 + 16) * 32;

  int mrow = lane & 15;
  int q = lane >> 4;
  int swz = (q ^ ((mrow >> 1) & 3)) * 8;
  const short8* ra = (const short8*)(As + (64 * wm + mrow) * 32 + swz);
  const short8* rb = (const short8*)(Bs + (64 * wn + mrow) * 32 + swz);

  f32x4 acc[4][4];
#pragma unroll
  for (int i = 0; i < 4; ++i)
#pragma unroll
    for (int j = 0; j < 4; ++j) acc[i][j] = (f32x4)(0.f);

  for (int k0 = 0; k0 < K; k0 += 32) {
    __syncthreads();
    __builtin_amdgcn_global_load_lds(GPTR(gA0 + k0), LPTR(lA0), 16, 0, 0);
    __builtin_amdgcn_global_load_lds(GPTR(gA1 + k0), LPTR(lA1), 16, 0, 0);
    __builtin_amdgcn_global_load_lds(GPTR(gB0 + k0), LPTR(lB0), 16, 0, 0);
    __builtin_amdgcn_global_load_lds(GPTR(gB1 + k0), LPTR(lB1), 16, 0, 0);
    __syncthreads();
    short8 a[4], b[4];
#pragma unroll
    for (int t = 0; t < 4; ++t) a[t] = ra[t * 64];
#pragma unroll
    for (int t = 0; t < 4; ++t) b[t] = rb[t * 64];
#pragma unroll
    for (int mt = 0; mt < 4; ++mt)
#pragma unroll
      for (int nt = 0; nt < 4; ++nt)
        acc[mt][nt] = __builtin_amdgcn_mfma_f32_16x16x32_bf16(a[mt], b[nt], acc[mt][nt], 0, 0, 0);
  }

  int colb = bcol * 128 + 64 * wn + (lane & 15);
  int rowb = brow * 128 + 64 * wm + 4 * q;
#pragma unroll
  for (int nt = 0; nt < 4; ++nt) {
    int col = colb + 16 * nt;
    float bv = bias ? bias[col] : 0.f;
#pragma unroll
    for (int mt = 0; mt < 4; ++mt) {
      int row = rowb + 16 * mt;
#pragma unroll
      for (int i = 0; i < 4; ++i)
        Cbf[(size_t)(row + i) * DIM_H + col] = f2bf(acc[mt][nt][i] + bv);
    }
  }
}

// ================= conversions =================
__global__ void convert_feat(const float* __restrict__ feat, unsigned short* __restrict__ Abf) {
  int t = blockIdx.x * blockDim.x + threadIdx.x;
  const int CHUNKS = M_PAD * DIM_IN / 8;
  if (t >= CHUNKS) return;
  int row = t / (DIM_IN / 8);
  uint4 o;
  if (row < N_NODES) {
    const float4* p = (const float4*)(feat + (size_t)t * 8);
    float4 x = p[0], y = p[1];
    o.x = (unsigned)f2bf(x.x) | ((unsigned)f2bf(x.y) << 16);
    o.y = (unsigned)f2bf(x.z) | ((unsigned)f2bf(x.w) << 16);
    o.z = (unsigned)f2bf(y.x) | ((unsigned)f2bf(y.y) << 16);
    o.w = (unsigned)f2bf(y.z) | ((unsigned)f2bf(y.w) << 16);
  } else {
    o = make_uint4(0, 0, 0, 0);
  }
  ((uint4*)Abf)[t] = o;
}

// LDS-tiled transpose: in [R,C] f32 -> out [C,R] bf16. R,C multiples of 32.
__global__ __launch_bounds__(256) void transpose_bf16(const float* __restrict__ in,
                                                      unsigned short* __restrict__ out,
                                                      int R, int C) {
  __shared__ float tile[32][33];
  int tx = threadIdx.x, ty = threadIdx.y;
  size_t base = (size_t)blockIdx.z * R * C;
  int r0 = blockIdx.x * 32, c0 = blockIdx.y * 32;
#pragma unroll
  for (int i = 0; i < 4; ++i) {
    int r = r0 + ty + i * 8;
    tile[ty + i * 8][tx] = in[base + (size_t)r * C + c0 + tx];
  }
  __syncthreads();
#pragma unroll
  for (int i = 0; i < 4; ++i) {
    int c = c0 + ty + i * 8;
    out[base + (size_t)c * R + r0 + tx] = f2bf(tile[tx][ty + i * 8]);
  }
}

// ================= CSR build (dst -> src adjacency) =================
__global__ void count_edges(const int* __restrict__ dst, int* __restrict__ counts) {
  int k = blockIdx.x * blockDim.x + threadIdx.x;
  if (k < N_EDGES) atomicAdd(&counts[dst[k]], 1);
}

__global__ __launch_bounds__(1024) void scan_kernel(const int* __restrict__ counts,
                                                    int* __restrict__ indptr) {
  __shared__ int part[1024];
  int tid = threadIdx.x;
  const int CH = (N_NODES + 1023) / 1024;
  int base = tid * CH;
  int s = 0;
  for (int i = 0; i < CH; ++i) {
    int idx = base + i;
    if (idx < N_NODES) s += counts[idx];
  }
  part[tid] = s;
  __syncthreads();
  for (int off = 1; off < 1024; off <<= 1) {
    int v = (tid >= off) ? part[tid - off] : 0;
    __syncthreads();
    part[tid] += v;
    __syncthreads();
  }
  int run = (tid == 0) ? 0 : part[tid - 1];
  for (int i = 0; i < CH; ++i) {
    int idx = base + i;
    if (idx < N_NODES) {
      indptr[idx] = run;
      run += counts[idx];
      if (idx == N_NODES - 1) indptr[N_NODES] = run;
    }
  }
}

__global__ void fill_adj(const int* __restrict__ src, const int* __restrict__ dst,
                         const int* __restrict__ indptr, int* __restrict__ cursor,
                         int* __restrict__ adjsrc) {
  int k = blockIdx.x * blockDim.x + threadIdx.x;
  if (k < N_EDGES) {
    int d = dst[k];
    int pos = atomicAdd(&cursor[d], 1);
    adjsrc[indptr[d] + pos] = src[k];
  }
}

// ================= el/er from bf16 z =================
__global__ __launch_bounds__(256) void eler_bf(const unsigned short* __restrict__ zbf,
                                               const float* __restrict__ al,
                                               const float* __restrict__ ar,
                                               float* __restrict__ el, float* __restrict__ er) {
  int wid = (blockIdx.x * blockDim.x + threadIdx.x) >> 6;
  int lane = threadIdx.x & 63;
  if (wid >= N_NODES) return;
  uint4 zv = ((const uint4*)(zbf + (size_t)wid * DIM_H))[lane];
  float z[8];
  unpack8(zv, z);
  const float4* al4 = (const float4*)(al + lane * 8);
  const float4* ar4 = (const float4*)(ar + lane * 8);
  float4 a0 = al4[0], a1 = al4[1], r0 = ar4[0], r1 = ar4[1];
  float sl = z[0] * a0.x + z[1] * a0.y + z[2] * a0.z + z[3] * a0.w +
             z[4] * a1.x + z[5] * a1.y + z[6] * a1.z + z[7] * a1.w;
  float sr = z[0] * r0.x + z[1] * r0.y + z[2] * r0.z + z[3] * r0.w +
             z[4] * r1.x + z[5] * r1.y + z[6] * r1.z + z[7] * r1.w;
  sl = waveReduceSum(sl);
  sr = waveReduceSum(sr);
  if (lane == 0) { el[wid] = sl; er[wid] = sr; }
}

// ================= edge softmax -> per-edge alpha =================
__global__ __launch_bounds__(256) void edge_softmax_alpha(
    const float* __restrict__ el, const float* __restrict__ er,
    const int* __restrict__ indptr, const int* __restrict__ adjsrc,
    float* __restrict__ alpha) {
  int v = (blockIdx.x * blockDim.x + threadIdx.x) >> 6;
  int lane = threadIdx.x & 63;
  if (v >= N_NODES) return;
  int begin = indptr[v], end = indptr[v + 1];
  float er_v = er[v];

  float m = -INFINITY;
  for (int j = begin + lane; j < end; j += 64) {
    float e = el[adjsrc[j]] + er_v;
    e = (e >= 0.f) ? e : NEG_SLOPE * e;
    m = fmaxf(m, e);
  }
  m = waveReduceMax(m);

  float ss = 0.f;
  for (int j = begin + lane; j < end; j += 64) {
    float e = el[adjsrc[j]] + er_v;
    e = (e >= 0.f) ? e : NEG_SLOPE * e;
    ss += __expf(e - m);
  }
  float denom = waveReduceSum(ss);
  float inv = (end > begin) ? 1.f / denom : 0.f;

  for (int j = begin + lane; j < end; j += 64) {
    float e = el[adjsrc[j]] + er_v;
    e = (e >= 0.f) ? e : NEG_SLOPE * e;
    alpha[j] = __expf(e - m) * inv;
  }
}

// ========== XCD-sliced weighted aggregate, scalar-index form ==========
// slice = bid&7 -> XCD. Each wave: 64 lanes = 64 cols of the slice, one edge at a
// time, wave-uniform edge index/weight (scalar loads) -> gather is one 128B line:
//   global_load_ushort v, v_col, s[row_base]  -- no shfl, no per-edge VALU addr.
// Each wave owns NPW consecutive nodes (contiguous adjacency stream).
__global__ __launch_bounds__(256) void gat_aggregate_slc(
    const unsigned short* __restrict__ zbf, const float* __restrict__ alpha,
    const int* __restrict__ indptr, const int* __restrict__ adjsrc,
    const float* __restrict__ bias, unsigned short* __restrict__ out_bf) {
  int slice = blockIdx.x & 7;
  int chunk = blockIdx.x >> 3;                 // 0..255
  int wave = threadIdx.x >> 6, lane = threadIdx.x & 63;
  int wid = chunk * 4 + wave;                  // 0..1023
  int col = slice * 64 + lane;
  float bv = bias[col];

  int v0 = wid * NPW;
  int v1 = min(v0 + NPW, N_NODES);
  for (int v = v0; v < v1; ++v) {
    int b = indptr[v], e = indptr[v + 1];
    float acc = 0.f;
    int j = b;
    for (; j + 8 <= e; j += 8) {
      int s0 = adjsrc[j + 0], s1 = adjsrc[j + 1], s2 = adjsrc[j + 2], s3 = adjsrc[j + 3];
      int s4 = adjsrc[j + 4], s5 = adjsrc[j + 5], s6 = adjsrc[j + 6], s7 = adjsrc[j + 7];
      float w0 = alpha[j + 0], w1 = alpha[j + 1], w2 = alpha[j + 2], w3 = alpha[j + 3];
      float w4 = alpha[j + 4], w5 = alpha[j + 5], w6 = alpha[j + 6], w7 = alpha[j + 7];
      float z0 = bf2f(zbf[(size_t)s0 * DIM_H + col]);
      float z1 = bf2f(zbf[(size_t)s1 * DIM_H + col]);
      float z2 = bf2f(zbf[(size_t)s2 * DIM_H + col]);
      float z3 = bf2f(zbf[(size_t)s3 * DIM_H + col]);
      float z4 = bf2f(zbf[(size_t)s4 * DIM_H + col]);
      float z5 = bf2f(zbf[(size_t)s5 * DIM_H + col]);
      float z6 = bf2f(zbf[(size_t)s6 * DIM_H + col]);
      float z7 = bf2f(zbf[(size_t)s7 * DIM_H + col]);
      acc += (w0 * z0 + w1 * z1) + (w2 * z2 + w3 * z3) +
             (w4 * z4 + w5 * z5) + (w6 * z6 + w7 * z7);
    }
    for (; j < e; ++j) {
      int s0 = adjsrc[j];
      acc += alpha[j] * bf2f(zbf[(size_t)s0 * DIM_H + col]);
    }
    out_bf[(size_t)v * DIM_H + col] = f2bf(acc + bv);
  }
}

// ========== XCD-sliced A_hat hop (out = z[v] + sum_{src} z[src]), scalar-index ==========
__global__ __launch_bounds__(256) void propagate_slc(
    const unsigned short* __restrict__ zin, const int* __restrict__ indptr,
    const int* __restrict__ adjsrc, unsigned short* __restrict__ out_bf,
    float* __restrict__ out_f32) {
  int slice = blockIdx.x & 7;
  int chunk = blockIdx.x >> 3;
  int wave = threadIdx.x >> 6, lane = threadIdx.x & 63;
  int wid = chunk * 4 + wave;
  int col = slice * 64 + lane;

  int v0 = wid * NPW;
  int v1 = min(v0 + NPW, N_NODES);
  for (int v = v0; v < v1; ++v) {
    int b = indptr[v], e = indptr[v + 1];
    float acc = bf2f(zin[(size_t)v * DIM_H + col]);   // self term (A_hat = A + I)
    int j = b;
    for (; j + 8 <= e; j += 8) {
      int s0 = adjsrc[j + 0], s1 = adjsrc[j + 1], s2 = adjsrc[j + 2], s3 = adjsrc[j + 3];
      int s4 = adjsrc[j + 4], s5 = adjsrc[j + 5], s6 = adjsrc[j + 6], s7 = adjsrc[j + 7];
      float z0 = bf2f(zin[(size_t)s0 * DIM_H + col]);
      float z1 = bf2f(zin[(size_t)s1 * DIM_H + col]);
      float z2 = bf2f(zin[(size_t)s2 * DIM_H + col]);
      float z3 = bf2f(zin[(size_t)s3 * DIM_H + col]);
      float z4 = bf2f(zin[(size_t)s4 * DIM_H + col]);
      float z5 = bf2f(zin[(size_t)s5 * DIM_H + col]);
      float z6 = bf2f(zin[(size_t)s6 * DIM_H + col]);
      float z7 = bf2f(zin[(size_t)s7 * DIM_H + col]);
      acc += ((z0 + z1) + (z2 + z3)) + ((z4 + z5) + (z6 + z7));
    }
    for (; j < e; ++j)
      acc += bf2f(zin[(size_t)adjsrc[j] * DIM_H + col]);
    if (out_bf) {
      out_bf[(size_t)v * DIM_H + col] = f2bf(acc);
    } else {
      out_f32[(size_t)v * DIM_H + col] = acc;
    }
  }
}

// ================= launch =================
extern "C" void kernel_launch(void* const* d_in, const int* in_sizes, int n_in,
                              void* d_out, int out_size, void* d_ws, size_t ws_size,
                              hipStream_t stream) {
  const float* feat = (const float*)d_in[0];
  const float* fc_W = (const float*)d_in[1];
  const float* fc_b = (const float*)d_in[2];
  const float* gat_W = (const float*)d_in[3];
  const float* gat_al = (const float*)d_in[4];
  const float* gat_ar = (const float*)d_in[5];
  const float* gat_b = (const float*)d_in[6];
  // d_in[7] = beta unused (reference returns Z_prev)
  const int* src = (const int*)d_in[8];
  const int* dst = (const int*)d_in[9];
  float* out = (float*)d_out;

  char* w = (char*)d_ws;
  auto alloc = [&](size_t bytes) {
    char* p = w;
    w += (bytes + 255) & ~(size_t)255;
    return p;
  };
  unsigned short* hbf   = (unsigned short*)alloc((size_t)M_PAD * DIM_H * 2);
  unsigned short* fcWt  = (unsigned short*)alloc((size_t)DIM_H * DIM_IN * 2);
  unsigned short* gatWt = (unsigned short*)alloc((size_t)NUM_GNNS * DIM_H * DIM_H * 2);
  float* el    = (float*)alloc((size_t)N_NODES * 4);
  float* er    = (float*)alloc((size_t)N_NODES * 4);
  int* counts  = (int*)alloc((size_t)2 * N_NODES * 4);   // counts+cursor contiguous
  int* cursor  = counts + N_NODES;
  int* indptr  = (int*)alloc((size_t)(N_NODES + 1) * 4);
  int* adjsrc  = (int*)alloc((size_t)N_EDGES * 4);
  char* uni = alloc((size_t)M_PAD * DIM_IN * 2);   // Abf (30.9 MB) -> alpha (1.28 MB) -> Z1 (20.6 MB)
  unsigned short* Abf = (unsigned short*)uni;      // live: convert + first GEMM only
  float* alpha = (float*)uni;                      // live: GAT layers only
  unsigned short* Z1  = (unsigned short*)uni;      // live: propagation only
  unsigned short* zbf = (unsigned short*)d_out;

  // ---- CSR build ----
  hipMemsetAsync(counts, 0, sizeof(int) * 2 * N_NODES, stream);
  count_edges<<<(N_EDGES + 255) / 256, 256, 0, stream>>>(dst, counts);
  scan_kernel<<<1, 1024, 0, stream>>>(counts, indptr);
  fill_adj<<<(N_EDGES + 255) / 256, 256, 0, stream>>>(src, dst, indptr, cursor, adjsrc);

  // ---- bf16 prep ----
  convert_feat<<<(M_PAD * DIM_IN / 8 + 255) / 256, 256, 0, stream>>>(feat, Abf);
  transpose_bf16<<<dim3(DIM_IN / 32, DIM_H / 32, 1), dim3(32, 8), 0, stream>>>(fc_W, fcWt, DIM_IN, DIM_H);
  transpose_bf16<<<dim3(DIM_H / 32, DIM_H / 32, NUM_GNNS), dim3(32, 8), 0, stream>>>(gat_W, gatWt, DIM_H, DIM_H);

  gemm_mfma_bf16<<<GEMM_GRID, 256, 0, stream>>>(Abf, fcWt, fc_b, hbf, DIM_IN);

  int nwaveblocks = (N_NODES * 64 + 255) / 256;
  for (int l = 0; l < NUM_GNNS; ++l) {
    gemm_mfma_bf16<<<GEMM_GRID, 256, 0, stream>>>(hbf, gatWt + (size_t)l * DIM_H * DIM_H,
                                                  nullptr, zbf, DIM_H);
    eler_bf<<<nwaveblocks, 256, 0, stream>>>(zbf, gat_al + (size_t)l * DIM_H,
                                             gat_ar + (size_t)l * DIM_H, el, er);
    edge_softmax_alpha<<<nwaveblocks, 256, 0, stream>>>(el, er, indptr, adjsrc, alpha);
    gat_aggregate_slc<<<SLC_GRID, 256, 0, stream>>>(
        zbf, alpha, indptr, adjsrc, gat_b + (size_t)l * DIM_H, hbf);
  }

  // ---- 3 propagation hops, XCD-sliced scalar-index ----
  propagate_slc<<<SLC_GRID, 256, 0, stream>>>(hbf, indptr, adjsrc, Z1, nullptr);
  propagate_slc<<<SLC_GRID, 256, 0, stream>>>(Z1, indptr, adjsrc, hbf, nullptr);
  propagate_slc<<<SLC_GRID, 256, 0, stream>>>(hbf, indptr, adjsrc, nullptr, out);
}

// Round 4
// 772.082 us; speedup vs baseline: 1.1641x; 1.1641x over previous
//
#include <hip/hip_runtime.h>
#include <math.h>

#define N_NODES 20000
#define M_PAD   20096   // 157 * 128
#define N_EDGES 320000
#define DIM_IN 768
#define DIM_H 512
#define NUM_GNNS 4
#define NEG_SLOPE 0.2f

#define GEMM_TILES 628        // (M_PAD/128) * (DIM_H/128) = 157*4
#define GEMM_GRID  632        // ceil to multiple of 8 for XCD swizzle

// sliced gather: 8 column slices (64 cols), slice = bid&7 -> XCD (round-robin).
// 1000 waves per slice, NPW consecutive nodes per wave. 2000 blocks x 4 waves.
#define NPW 20
#define SLC_GRID 2000

typedef __attribute__((ext_vector_type(8))) short short8;
typedef __attribute__((ext_vector_type(4))) float f32x4;
typedef __attribute__((ext_vector_type(4))) unsigned int u32x4;

#define GPTR(p) (const __attribute__((address_space(1))) void*)(p)
#define LPTR(p) (__attribute__((address_space(3))) void*)(p)

__device__ __forceinline__ float bf2f(unsigned int lo16) {
  return __uint_as_float(lo16 << 16);
}
__device__ __forceinline__ unsigned short f2bf(float f) {
  unsigned int u = __float_as_uint(f);
  u += 0x7FFFu + ((u >> 16) & 1u);   // round-to-nearest-even
  return (unsigned short)(u >> 16);
}
__device__ __forceinline__ void unpack8(uint4 v, float* f) {
  f[0] = bf2f(v.x & 0xffffu); f[1] = bf2f(v.x >> 16);
  f[2] = bf2f(v.y & 0xffffu); f[3] = bf2f(v.y >> 16);
  f[4] = bf2f(v.z & 0xffffu); f[5] = bf2f(v.z >> 16);
  f[6] = bf2f(v.w & 0xffffu); f[7] = bf2f(v.w >> 16);
}
__device__ __forceinline__ uint4 pack8(const float* o) {
  uint4 pv;
  pv.x = (unsigned)f2bf(o[0]) | ((unsigned)f2bf(o[1]) << 16);
  pv.y = (unsigned)f2bf(o[2]) | ((unsigned)f2bf(o[3]) << 16);
  pv.z = (unsigned)f2bf(o[4]) | ((unsigned)f2bf(o[5]) << 16);
  pv.w = (unsigned)f2bf(o[6]) | ((unsigned)f2bf(o[7]) << 16);
  return pv;
}

__device__ __forceinline__ float waveReduceSum(float v) {
#pragma unroll
  for (int off = 32; off > 0; off >>= 1) v += __shfl_xor(v, off, 64);
  return v;
}
__device__ __forceinline__ float waveReduceMax(float v) {
#pragma unroll
  for (int off = 32; off > 0; off >>= 1) v = fmaxf(v, __shfl_xor(v, off, 64));
  return v;
}

// ================= MFMA GEMM (lean) + XCD tile swizzle =================
__global__ __launch_bounds__(256) void gemm_mfma_bf16(
    const unsigned short* __restrict__ A,
    const unsigned short* __restrict__ Bt,
    const float* __restrict__ bias,
    unsigned short* __restrict__ Cbf,
    int K) {
  int bid = blockIdx.x;
  int tile = (bid & 7) * (GEMM_GRID / 8) + (bid >> 3);
  if (tile >= GEMM_TILES) return;
  int brow = tile >> 2;   // 0..156
  int bcol = tile & 3;    // 0..3

  __shared__ __align__(16) unsigned short As[128 * 32];
  __shared__ __align__(16) unsigned short Bs[128 * 32];
  int tid = threadIdx.x;
  int wave = tid >> 6, lane = tid & 63;
  int wm = wave >> 1, wn = wave & 1;

  int rl = lane >> 2;
  int kc = (lane & 3) ^ ((lane >> 3) & 3);
  int r0 = 32 * wave;
  const unsigned short* gA0 = A + (size_t)(brow * 128 + r0 + rl) * K + kc * 8;
  const unsigned short* gA1 = gA0 + (size_t)16 * K;
  const unsigned short* gB0 = Bt + (size_t)(bcol * 128 + r0 + rl) * K + kc * 8;
  const unsigned short* gB1 = gB0 + (size_t)16 * K;
  unsigned short* lA0 = As + r0 * 32;
  unsigned short* lA1 = As + (r0 + 16) * 32;
  unsigned short* lB0 = Bs + r0 * 32;
  unsigned short* lB1 = Bs + (r0 + 16) * 32;

  int mrow = lane & 15;
  int q = lane >> 4;
  int swz = (q ^ ((mrow >> 1) & 3)) * 8;
  const short8* ra = (const short8*)(As + (64 * wm + mrow) * 32 + swz);
  const short8* rb = (const short8*)(Bs + (64 * wn + mrow) * 32 + swz);

  f32x4 acc[4][4];
#pragma unroll
  for (int i = 0; i < 4; ++i)
#pragma unroll
    for (int j = 0; j < 4; ++j) acc[i][j] = (f32x4)(0.f);

  for (int k0 = 0; k0 < K; k0 += 32) {
    __syncthreads();
    __builtin_amdgcn_global_load_lds(GPTR(gA0 + k0), LPTR(lA0), 16, 0, 0);
    __builtin_amdgcn_global_load_lds(GPTR(gA1 + k0), LPTR(lA1), 16, 0, 0);
    __builtin_amdgcn_global_load_lds(GPTR(gB0 + k0), LPTR(lB0), 16, 0, 0);
    __builtin_amdgcn_global_load_lds(GPTR(gB1 + k0), LPTR(lB1), 16, 0, 0);
    __syncthreads();
    short8 a[4], b[4];
#pragma unroll
    for (int t = 0; t < 4; ++t) a[t] = ra[t * 64];
#pragma unroll
    for (int t = 0; t < 4; ++t) b[t] = rb[t * 64];
#pragma unroll
    for (int mt = 0; mt < 4; ++mt)
#pragma unroll
      for (int nt = 0; nt < 4; ++nt)
        acc[mt][nt] = __builtin_amdgcn_mfma_f32_16x16x32_bf16(a[mt], b[nt], acc[mt][nt], 0, 0, 0);
  }

  int colb = bcol * 128 + 64 * wn + (lane & 15);
  int rowb = brow * 128 + 64 * wm + 4 * q;
#pragma unroll
  for (int nt = 0; nt < 4; ++nt) {
    int col = colb + 16 * nt;
    float bv = bias ? bias[col] : 0.f;
#pragma unroll
    for (int mt = 0; mt < 4; ++mt) {
      int row = rowb + 16 * mt;
#pragma unroll
      for (int i = 0; i < 4; ++i)
        Cbf[(size_t)(row + i) * DIM_H + col] = f2bf(acc[mt][nt][i] + bv);
    }
  }
}

// ================= conversions =================
__global__ void convert_feat(const float* __restrict__ feat, unsigned short* __restrict__ Abf) {
  int t = blockIdx.x * blockDim.x + threadIdx.x;
  const int CHUNKS = M_PAD * DIM_IN / 8;
  if (t >= CHUNKS) return;
  int row = t / (DIM_IN / 8);
  uint4 o;
  if (row < N_NODES) {
    const float4* p = (const float4*)(feat + (size_t)t * 8);
    float4 x = p[0], y = p[1];
    o.x = (unsigned)f2bf(x.x) | ((unsigned)f2bf(x.y) << 16);
    o.y = (unsigned)f2bf(x.z) | ((unsigned)f2bf(x.w) << 16);
    o.z = (unsigned)f2bf(y.x) | ((unsigned)f2bf(y.y) << 16);
    o.w = (unsigned)f2bf(y.z) | ((unsigned)f2bf(y.w) << 16);
  } else {
    o = make_uint4(0, 0, 0, 0);
  }
  ((uint4*)Abf)[t] = o;
}

// LDS-tiled transpose: in [R,C] f32 -> out [C,R] bf16. R,C multiples of 32.
__global__ __launch_bounds__(256) void transpose_bf16(const float* __restrict__ in,
                                                      unsigned short* __restrict__ out,
                                                      int R, int C) {
  __shared__ float tile[32][33];
  int tx = threadIdx.x, ty = threadIdx.y;
  size_t base = (size_t)blockIdx.z * R * C;
  int r0 = blockIdx.x * 32, c0 = blockIdx.y * 32;
#pragma unroll
  for (int i = 0; i < 4; ++i) {
    int r = r0 + ty + i * 8;
    tile[ty + i * 8][tx] = in[base + (size_t)r * C + c0 + tx];
  }
  __syncthreads();
#pragma unroll
  for (int i = 0; i < 4; ++i) {
    int c = c0 + ty + i * 8;
    out[base + (size_t)c * R + r0 + tx] = f2bf(tile[tx][ty + i * 8]);
  }
}

// ================= CSR build (dst -> src adjacency) =================
__global__ void count_edges(const int* __restrict__ dst, int* __restrict__ counts) {
  int k = blockIdx.x * blockDim.x + threadIdx.x;
  if (k < N_EDGES) atomicAdd(&counts[dst[k]], 1);
}

__global__ __launch_bounds__(1024) void scan_kernel(const int* __restrict__ counts,
                                                    int* __restrict__ indptr) {
  __shared__ int part[1024];
  int tid = threadIdx.x;
  const int CH = (N_NODES + 1023) / 1024;
  int base = tid * CH;
  int s = 0;
  for (int i = 0; i < CH; ++i) {
    int idx = base + i;
    if (idx < N_NODES) s += counts[idx];
  }
  part[tid] = s;
  __syncthreads();
  for (int off = 1; off < 1024; off <<= 1) {
    int v = (tid >= off) ? part[tid - off] : 0;
    __syncthreads();
    part[tid] += v;
    __syncthreads();
  }
  int run = (tid == 0) ? 0 : part[tid - 1];
  for (int i = 0; i < CH; ++i) {
    int idx = base + i;
    if (idx < N_NODES) {
      indptr[idx] = run;
      run += counts[idx];
      if (idx == N_NODES - 1) indptr[N_NODES] = run;
    }
  }
}

__global__ void fill_adj(const int* __restrict__ src, const int* __restrict__ dst,
                         const int* __restrict__ indptr, int* __restrict__ cursor,
                         int* __restrict__ adjsrc) {
  int k = blockIdx.x * blockDim.x + threadIdx.x;
  if (k < N_EDGES) {
    int d = dst[k];
    int pos = atomicAdd(&cursor[d], 1);
    adjsrc[indptr[d] + pos] = src[k];
  }
}

// ================= el/er from bf16 z =================
__global__ __launch_bounds__(256) void eler_bf(const unsigned short* __restrict__ zbf,
                                               const float* __restrict__ al,
                                               const float* __restrict__ ar,
                                               float* __restrict__ el, float* __restrict__ er) {
  int wid = (blockIdx.x * blockDim.x + threadIdx.x) >> 6;
  int lane = threadIdx.x & 63;
  if (wid >= N_NODES) return;
  uint4 zv = ((const uint4*)(zbf + (size_t)wid * DIM_H))[lane];
  float z[8];
  unpack8(zv, z);
  const float4* al4 = (const float4*)(al + lane * 8);
  const float4* ar4 = (const float4*)(ar + lane * 8);
  float4 a0 = al4[0], a1 = al4[1], r0 = ar4[0], r1 = ar4[1];
  float sl = z[0] * a0.x + z[1] * a0.y + z[2] * a0.z + z[3] * a0.w +
             z[4] * a1.x + z[5] * a1.y + z[6] * a1.z + z[7] * a1.w;
  float sr = z[0] * r0.x + z[1] * r0.y + z[2] * r0.z + z[3] * r0.w +
             z[4] * r1.x + z[5] * r1.y + z[6] * r1.z + z[7] * r1.w;
  sl = waveReduceSum(sl);
  sr = waveReduceSum(sr);
  if (lane == 0) { el[wid] = sl; er[wid] = sr; }
}

// ================= edge softmax -> per-edge alpha =================
// pass1: max; pass2: exp -> alpha + sum; pass3: scale alpha in place (no gather)
__global__ __launch_bounds__(256) void edge_softmax_alpha(
    const float* __restrict__ el, const float* __restrict__ er,
    const int* __restrict__ indptr, const int* __restrict__ adjsrc,
    float* __restrict__ alpha) {
  int v = (blockIdx.x * blockDim.x + threadIdx.x) >> 6;
  int lane = threadIdx.x & 63;
  if (v >= N_NODES) return;
  int begin = indptr[v], end = indptr[v + 1];
  float er_v = er[v];

  float m = -INFINITY;
  for (int j = begin + lane; j < end; j += 64) {
    float e = el[adjsrc[j]] + er_v;
    e = (e >= 0.f) ? e : NEG_SLOPE * e;
    m = fmaxf(m, e);
  }
  m = waveReduceMax(m);

  float ss = 0.f;
  for (int j = begin + lane; j < end; j += 64) {
    float e = el[adjsrc[j]] + er_v;
    e = (e >= 0.f) ? e : NEG_SLOPE * e;
    float ex = __expf(e - m);
    alpha[j] = ex;
    ss += ex;
  }
  float denom = waveReduceSum(ss);
  float inv = (end > begin) ? 1.f / denom : 0.f;

  for (int j = begin + lane; j < end; j += 64) alpha[j] *= inv;
}

// ========== unified XCD-sliced gather (GAT aggregate / A_hat hop) ==========
// slice = bid&7 -> XCD: each XCD gathers from a 20000 x 64col x 2B = 2.56 MB
// slice of zin (fits the 4 MiB private L2). Layout: 8 slots x 8 lanes x uint4;
// one gather instruction = 8 rows x 128B. All hot addresses are
// uniform_base + 32-bit voffset so codegen is global_load saddr form
// (no per-lane 64-bit address arithmetic — the R2/R3 killer).
// alpha==null -> weight 1 (propagate); self_term adds zin[v]; bias optional;
// out_bf!=null -> bf16 out else f32 out.
__global__ __launch_bounds__(256) void gather_slc(
    const unsigned short* __restrict__ zin, const float* __restrict__ alpha,
    const int* __restrict__ indptr, const int* __restrict__ adjsrc,
    const float* __restrict__ bias, int self_term,
    unsigned short* __restrict__ out_bf, float* __restrict__ out_f32) {
  int slice = blockIdx.x & 7;
  int wid = (blockIdx.x >> 3) * 4 + (threadIdx.x >> 6);   // 0..999
  int lane = threadIdx.x & 63;
  int slot = lane >> 3, sub = lane & 7;
  unsigned cbyte = (unsigned)(slice * 128 + sub * 16);    // this lane's 8 cols (bytes)
  const char* zb = (const char*)zin;
  const char* ab = (const char*)adjsrc;
  const char* wb = (const char*)alpha;
  float smask = (self_term && slot == 0) ? 1.f : 0.f;
  float bv[8] = {0.f, 0.f, 0.f, 0.f, 0.f, 0.f, 0.f, 0.f};
  if (bias) {
    const float4* b4 = (const float4*)(bias + slice * 64 + sub * 8);
    float4 b0 = b4[0], b1 = b4[1];
    bv[0] = b0.x; bv[1] = b0.y; bv[2] = b0.z; bv[3] = b0.w;
    bv[4] = b1.x; bv[5] = b1.y; bv[6] = b1.z; bv[7] = b1.w;
  }
  const unsigned AMAXB = (unsigned)(N_EDGES - 1) * 4u;

  int v0 = wid * NPW;
#pragma nounroll
  for (int v = v0; v < v0 + NPW; ++v) {
    int b = indptr[v], e = indptr[v + 1];
    float acc[8];
    {
      uint4 sz = *(const uint4*)(zb + (((unsigned)v) << 10) + cbyte);
      float f[8];
      unpack8(sz, f);
#pragma unroll
      for (int i = 0; i < 8; ++i) acc[i] = smask * f[i];
    }
    int j = b;
    for (; j + 16 <= e; j += 16) {          // 2 gathers in flight
      unsigned a0 = (unsigned)(j + slot) * 4u;
      unsigned a1 = a0 + 32u;
      int i0 = *(const int*)(ab + a0);
      int i1 = *(const int*)(ab + a1);
      float w0 = alpha ? *(const float*)(wb + a0) : 1.f;
      float w1 = alpha ? *(const float*)(wb + a1) : 1.f;
      uint4 z0 = *(const uint4*)(zb + ((unsigned)i0 << 10) + cbyte);
      uint4 z1 = *(const uint4*)(zb + ((unsigned)i1 << 10) + cbyte);
      float f0[8], f1[8];
      unpack8(z0, f0);
      unpack8(z1, f1);
#pragma unroll
      for (int i = 0; i < 8; ++i) acc[i] = fmaf(w0, f0[i], fmaf(w1, f1[i], acc[i]));
    }
    for (; j < e; j += 8) {                 // masked tail
      int eidx = j + slot;
      unsigned a0 = min((unsigned)eidx * 4u, AMAXB);
      int i0 = *(const int*)(ab + a0);
      float wraw = alpha ? *(const float*)(wb + a0) : 1.f;
      float w0 = (eidx < e) ? wraw : 0.f;
      uint4 z0 = *(const uint4*)(zb + ((unsigned)i0 << 10) + cbyte);
      float f0[8];
      unpack8(z0, f0);
#pragma unroll
      for (int i = 0; i < 8; ++i) acc[i] = fmaf(w0, f0[i], acc[i]);
    }
#pragma unroll
    for (int i = 0; i < 8; ++i) {
      acc[i] += __shfl_xor(acc[i], 8, 64);
      acc[i] += __shfl_xor(acc[i], 16, 64);
      acc[i] += __shfl_xor(acc[i], 32, 64);
    }
    if (slot == 0) {
      if (out_bf) {
        float o[8];
#pragma unroll
        for (int i = 0; i < 8; ++i) o[i] = acc[i] + bv[i];
        uint4 pv = pack8(o);
        u32x4 sv = {pv.x, pv.y, pv.z, pv.w};
        __builtin_nontemporal_store(sv, (u32x4*)((char*)out_bf + (((unsigned)v) << 10) + cbyte));
      } else {
        f32x4 lo = {acc[0], acc[1], acc[2], acc[3]};
        f32x4 hi = {acc[4], acc[5], acc[6], acc[7]};
        char* p = (char*)out_f32 + (((unsigned)v) << 11) + cbyte * 2;
        __builtin_nontemporal_store(lo, (f32x4*)p);
        __builtin_nontemporal_store(hi, (f32x4*)(p + 16));
      }
    }
  }
}

// ================= launch =================
extern "C" void kernel_launch(void* const* d_in, const int* in_sizes, int n_in,
                              void* d_out, int out_size, void* d_ws, size_t ws_size,
                              hipStream_t stream) {
  const float* feat = (const float*)d_in[0];
  const float* fc_W = (const float*)d_in[1];
  const float* fc_b = (const float*)d_in[2];
  const float* gat_W = (const float*)d_in[3];
  const float* gat_al = (const float*)d_in[4];
  const float* gat_ar = (const float*)d_in[5];
  const float* gat_b = (const float*)d_in[6];
  // d_in[7] = beta unused (reference returns Z_prev)
  const int* src = (const int*)d_in[8];
  const int* dst = (const int*)d_in[9];
  float* out = (float*)d_out;

  char* w = (char*)d_ws;
  auto alloc = [&](size_t bytes) {
    char* p = w;
    w += (bytes + 255) & ~(size_t)255;
    return p;
  };
  unsigned short* hbf   = (unsigned short*)alloc((size_t)M_PAD * DIM_H * 2);
  unsigned short* fcWt  = (unsigned short*)alloc((size_t)DIM_H * DIM_IN * 2);
  unsigned short* gatWt = (unsigned short*)alloc((size_t)NUM_GNNS * DIM_H * DIM_H * 2);
  float* el    = (float*)alloc((size_t)N_NODES * 4);
  float* er    = (float*)alloc((size_t)N_NODES * 4);
  int* counts  = (int*)alloc((size_t)2 * N_NODES * 4);   // counts+cursor contiguous
  int* cursor  = counts + N_NODES;
  int* indptr  = (int*)alloc((size_t)(N_NODES + 1) * 4);
  int* adjsrc  = (int*)alloc((size_t)N_EDGES * 4);
  char* uni = alloc((size_t)M_PAD * DIM_IN * 2);   // Abf (30.9 MB) -> alpha (1.28 MB) -> Z1 (20.6 MB)
  unsigned short* Abf = (unsigned short*)uni;      // live: convert + first GEMM only
  float* alpha = (float*)uni;                      // live: GAT layers only
  unsigned short* Z1  = (unsigned short*)uni;      // live: propagation only
  unsigned short* zbf = (unsigned short*)d_out;

  // ---- CSR build ----
  hipMemsetAsync(counts, 0, sizeof(int) * 2 * N_NODES, stream);
  count_edges<<<(N_EDGES + 255) / 256, 256, 0, stream>>>(dst, counts);
  scan_kernel<<<1, 1024, 0, stream>>>(counts, indptr);
  fill_adj<<<(N_EDGES + 255) / 256, 256, 0, stream>>>(src, dst, indptr, cursor, adjsrc);

  // ---- bf16 prep ----
  convert_feat<<<(M_PAD * DIM_IN / 8 + 255) / 256, 256, 0, stream>>>(feat, Abf);
  transpose_bf16<<<dim3(DIM_IN / 32, DIM_H / 32, 1), dim3(32, 8), 0, stream>>>(fc_W, fcWt, DIM_IN, DIM_H);
  transpose_bf16<<<dim3(DIM_H / 32, DIM_H / 32, NUM_GNNS), dim3(32, 8), 0, stream>>>(gat_W, gatWt, DIM_H, DIM_H);

  gemm_mfma_bf16<<<GEMM_GRID, 256, 0, stream>>>(Abf, fcWt, fc_b, hbf, DIM_IN);

  int nwaveblocks = (N_NODES * 64 + 255) / 256;
  for (int l = 0; l < NUM_GNNS; ++l) {
    gemm_mfma_bf16<<<GEMM_GRID, 256, 0, stream>>>(hbf, gatWt + (size_t)l * DIM_H * DIM_H,
                                                  nullptr, zbf, DIM_H);
    eler_bf<<<nwaveblocks, 256, 0, stream>>>(zbf, gat_al + (size_t)l * DIM_H,
                                             gat_ar + (size_t)l * DIM_H, el, er);
    edge_softmax_alpha<<<nwaveblocks, 256, 0, stream>>>(el, er, indptr, adjsrc, alpha);
    gather_slc<<<SLC_GRID, 256, 0, stream>>>(
        zbf, alpha, indptr, adjsrc, gat_b + (size_t)l * DIM_H, 0, hbf, nullptr);
  }

  // ---- 3 propagation hops (self term, weight 1) ----
  gather_slc<<<SLC_GRID, 256, 0, stream>>>(hbf, nullptr, indptr, adjsrc, nullptr, 1, Z1, nullptr);
  gather_slc<<<SLC_GRID, 256, 0, stream>>>(Z1, nullptr, indptr, adjsrc, nullptr, 1, hbf, nullptr);
  gather_slc<<<SLC_GRID, 256, 0, stream>>>(hbf, nullptr, indptr, adjsrc, nullptr, 1, nullptr, out);
}

// Round 5
// 582.487 us; speedup vs baseline: 1.5429x; 1.3255x over previous
//
#include <hip/hip_runtime.h>
#include <math.h>

#define N_NODES 20000
#define M_PAD   20096   // 157 * 128
#define N_EDGES 320000
#define DIM_IN 768
#define DIM_H 512
#define NUM_GNNS 4
#define NEG_SLOPE 0.2f

#define GEMM_TILES 628        // (M_PAD/128) * (DIM_H/128) = 157*4
#define GEMM_GRID  632        // ceil to multiple of 8 for XCD swizzle

// sliced gather: 8 column slices (64 cols), slice = bid&7 -> XCD (round-robin).
// grid = 8 slices * 625 node-groups; block = 4 waves; wave = 8 slots * 8 subs;
// slot owns ONE node (8 consecutive nodes per wave), sub owns 8 cols (uint4).
#define SLC_GRID 5000

typedef __attribute__((ext_vector_type(8))) short short8;
typedef __attribute__((ext_vector_type(4))) float f32x4;
typedef __attribute__((ext_vector_type(4))) unsigned int u32x4;

#define GPTR(p) (const __attribute__((address_space(1))) void*)(p)
#define LPTR(p) (__attribute__((address_space(3))) void*)(p)

__device__ __forceinline__ float bf2f(unsigned int lo16) {
  return __uint_as_float(lo16 << 16);
}
__device__ __forceinline__ unsigned short f2bf(float f) {
  unsigned int u = __float_as_uint(f);
  u += 0x7FFFu + ((u >> 16) & 1u);   // round-to-nearest-even
  return (unsigned short)(u >> 16);
}
__device__ __forceinline__ void unpack8(uint4 v, float* f) {
  f[0] = bf2f(v.x & 0xffffu); f[1] = bf2f(v.x >> 16);
  f[2] = bf2f(v.y & 0xffffu); f[3] = bf2f(v.y >> 16);
  f[4] = bf2f(v.z & 0xffffu); f[5] = bf2f(v.z >> 16);
  f[6] = bf2f(v.w & 0xffffu); f[7] = bf2f(v.w >> 16);
}
__device__ __forceinline__ uint4 pack8(const float* o) {
  uint4 pv;
  pv.x = (unsigned)f2bf(o[0]) | ((unsigned)f2bf(o[1]) << 16);
  pv.y = (unsigned)f2bf(o[2]) | ((unsigned)f2bf(o[3]) << 16);
  pv.z = (unsigned)f2bf(o[4]) | ((unsigned)f2bf(o[5]) << 16);
  pv.w = (unsigned)f2bf(o[6]) | ((unsigned)f2bf(o[7]) << 16);
  return pv;
}

__device__ __forceinline__ float waveReduceSum(float v) {
#pragma unroll
  for (int off = 32; off > 0; off >>= 1) v += __shfl_xor(v, off, 64);
  return v;
}
__device__ __forceinline__ float waveReduceMax(float v) {
#pragma unroll
  for (int off = 32; off > 0; off >>= 1) v = fmaxf(v, __shfl_xor(v, off, 64));
  return v;
}

// ================= MFMA GEMM (lean) + XCD tile swizzle =================
__global__ __launch_bounds__(256) void gemm_mfma_bf16(
    const unsigned short* __restrict__ A,
    const unsigned short* __restrict__ Bt,
    const float* __restrict__ bias,
    unsigned short* __restrict__ Cbf,
    int K) {
  int bid = blockIdx.x;
  int tile = (bid & 7) * (GEMM_GRID / 8) + (bid >> 3);
  if (tile >= GEMM_TILES) return;
  int brow = tile >> 2;   // 0..156
  int bcol = tile & 3;    // 0..3

  __shared__ __align__(16) unsigned short As[128 * 32];
  __shared__ __align__(16) unsigned short Bs[128 * 32];
  int tid = threadIdx.x;
  int wave = tid >> 6, lane = tid & 63;
  int wm = wave >> 1, wn = wave & 1;

  int rl = lane >> 2;
  int kc = (lane & 3) ^ ((lane >> 3) & 3);
  int r0 = 32 * wave;
  const unsigned short* gA0 = A + (size_t)(brow * 128 + r0 + rl) * K + kc * 8;
  const unsigned short* gA1 = gA0 + (size_t)16 * K;
  const unsigned short* gB0 = Bt + (size_t)(bcol * 128 + r0 + rl) * K + kc * 8;
  const unsigned short* gB1 = gB0 + (size_t)16 * K;
  unsigned short* lA0 = As + r0 * 32;
  unsigned short* lA1 = As + (r0 + 16) * 32;
  unsigned short* lB0 = Bs + r0 * 32;
  unsigned short* lB1 = Bs + (r0 + 16) * 32;

  int mrow = lane & 15;
  int q = lane >> 4;
  int swz = (q ^ ((mrow >> 1) & 3)) * 8;
  const short8* ra = (const short8*)(As + (64 * wm + mrow) * 32 + swz);
  const short8* rb = (const short8*)(Bs + (64 * wn + mrow) * 32 + swz);

  f32x4 acc[4][4];
#pragma unroll
  for (int i = 0; i < 4; ++i)
#pragma unroll
    for (int j = 0; j < 4; ++j) acc[i][j] = (f32x4)(0.f);

  for (int k0 = 0; k0 < K; k0 += 32) {
    __syncthreads();
    __builtin_amdgcn_global_load_lds(GPTR(gA0 + k0), LPTR(lA0), 16, 0, 0);
    __builtin_amdgcn_global_load_lds(GPTR(gA1 + k0), LPTR(lA1), 16, 0, 0);
    __builtin_amdgcn_global_load_lds(GPTR(gB0 + k0), LPTR(lB0), 16, 0, 0);
    __builtin_amdgcn_global_load_lds(GPTR(gB1 + k0), LPTR(lB1), 16, 0, 0);
    __syncthreads();
    short8 a[4], b[4];
#pragma unroll
    for (int t = 0; t < 4; ++t) a[t] = ra[t * 64];
#pragma unroll
    for (int t = 0; t < 4; ++t) b[t] = rb[t * 64];
#pragma unroll
    for (int mt = 0; mt < 4; ++mt)
#pragma unroll
      for (int nt = 0; nt < 4; ++nt)
        acc[mt][nt] = __builtin_amdgcn_mfma_f32_16x16x32_bf16(a[mt], b[nt], acc[mt][nt], 0, 0, 0);
  }

  int colb = bcol * 128 + 64 * wn + (lane & 15);
  int rowb = brow * 128 + 64 * wm + 4 * q;
#pragma unroll
  for (int nt = 0; nt < 4; ++nt) {
    int col = colb + 16 * nt;
    float bv = bias ? bias[col] : 0.f;
#pragma unroll
    for (int mt = 0; mt < 4; ++mt) {
      int row = rowb + 16 * mt;
#pragma unroll
      for (int i = 0; i < 4; ++i)
        Cbf[(size_t)(row + i) * DIM_H + col] = f2bf(acc[mt][nt][i] + bv);
    }
  }
}

// ================= conversions =================
__global__ void convert_feat(const float* __restrict__ feat, unsigned short* __restrict__ Abf) {
  int t = blockIdx.x * blockDim.x + threadIdx.x;
  const int CHUNKS = M_PAD * DIM_IN / 8;
  if (t >= CHUNKS) return;
  int row = t / (DIM_IN / 8);
  uint4 o;
  if (row < N_NODES) {
    const float4* p = (const float4*)(feat + (size_t)t * 8);
    float4 x = p[0], y = p[1];
    o.x = (unsigned)f2bf(x.x) | ((unsigned)f2bf(x.y) << 16);
    o.y = (unsigned)f2bf(x.z) | ((unsigned)f2bf(x.w) << 16);
    o.z = (unsigned)f2bf(y.x) | ((unsigned)f2bf(y.y) << 16);
    o.w = (unsigned)f2bf(y.z) | ((unsigned)f2bf(y.w) << 16);
  } else {
    o = make_uint4(0, 0, 0, 0);
  }
  ((uint4*)Abf)[t] = o;
}

// LDS-tiled transpose: in [R,C] f32 -> out [C,R] bf16. R,C multiples of 32.
__global__ __launch_bounds__(256) void transpose_bf16(const float* __restrict__ in,
                                                      unsigned short* __restrict__ out,
                                                      int R, int C) {
  __shared__ float tile[32][33];
  int tx = threadIdx.x, ty = threadIdx.y;
  size_t base = (size_t)blockIdx.z * R * C;
  int r0 = blockIdx.x * 32, c0 = blockIdx.y * 32;
#pragma unroll
  for (int i = 0; i < 4; ++i) {
    int r = r0 + ty + i * 8;
    tile[ty + i * 8][tx] = in[base + (size_t)r * C + c0 + tx];
  }
  __syncthreads();
#pragma unroll
  for (int i = 0; i < 4; ++i) {
    int c = c0 + ty + i * 8;
    out[base + (size_t)c * R + r0 + tx] = f2bf(tile[tx][ty + i * 8]);
  }
}

// ================= CSR build (dst -> src adjacency) =================
__global__ void count_edges(const int* __restrict__ dst, int* __restrict__ counts) {
  int k = blockIdx.x * blockDim.x + threadIdx.x;
  if (k < N_EDGES) atomicAdd(&counts[dst[k]], 1);
}

__global__ __launch_bounds__(1024) void scan_kernel(const int* __restrict__ counts,
                                                    int* __restrict__ indptr) {
  __shared__ int part[1024];
  int tid = threadIdx.x;
  const int CH = (N_NODES + 1023) / 1024;
  int base = tid * CH;
  int s = 0;
  for (int i = 0; i < CH; ++i) {
    int idx = base + i;
    if (idx < N_NODES) s += counts[idx];
  }
  part[tid] = s;
  __syncthreads();
  for (int off = 1; off < 1024; off <<= 1) {
    int v = (tid >= off) ? part[tid - off] : 0;
    __syncthreads();
    part[tid] += v;
    __syncthreads();
  }
  int run = (tid == 0) ? 0 : part[tid - 1];
  for (int i = 0; i < CH; ++i) {
    int idx = base + i;
    if (idx < N_NODES) {
      indptr[idx] = run;
      run += counts[idx];
      if (idx == N_NODES - 1) indptr[N_NODES] = run;
    }
  }
}

__global__ void fill_adj(const int* __restrict__ src, const int* __restrict__ dst,
                         const int* __restrict__ indptr, int* __restrict__ cursor,
                         int* __restrict__ adjsrc) {
  int k = blockIdx.x * blockDim.x + threadIdx.x;
  if (k < N_EDGES) {
    int d = dst[k];
    int pos = atomicAdd(&cursor[d], 1);
    adjsrc[indptr[d] + pos] = src[k];
  }
}

// ================= el/er from bf16 z =================
__global__ __launch_bounds__(256) void eler_bf(const unsigned short* __restrict__ zbf,
                                               const float* __restrict__ al,
                                               const float* __restrict__ ar,
                                               float* __restrict__ el, float* __restrict__ er) {
  int wid = (blockIdx.x * blockDim.x + threadIdx.x) >> 6;
  int lane = threadIdx.x & 63;
  if (wid >= N_NODES) return;
  uint4 zv = ((const uint4*)(zbf + (size_t)wid * DIM_H))[lane];
  float z[8];
  unpack8(zv, z);
  const float4* al4 = (const float4*)(al + lane * 8);
  const float4* ar4 = (const float4*)(ar + lane * 8);
  float4 a0 = al4[0], a1 = al4[1], r0 = ar4[0], r1 = ar4[1];
  float sl = z[0] * a0.x + z[1] * a0.y + z[2] * a0.z + z[3] * a0.w +
             z[4] * a1.x + z[5] * a1.y + z[6] * a1.z + z[7] * a1.w;
  float sr = z[0] * r0.x + z[1] * r0.y + z[2] * r0.z + z[3] * r0.w +
             z[4] * r1.x + z[5] * r1.y + z[6] * r1.z + z[7] * r1.w;
  sl = waveReduceSum(sl);
  sr = waveReduceSum(sr);
  if (lane == 0) { el[wid] = sl; er[wid] = sr; }
}

// ================= edge softmax -> per-edge alpha =================
// pass1: gather el, leaky, stash e in alpha, max; pass2 (sequential): exp+sum;
// pass3 (sequential): scale.
__global__ __launch_bounds__(256) void edge_softmax_alpha(
    const float* __restrict__ el, const float* __restrict__ er,
    const int* __restrict__ indptr, const int* __restrict__ adjsrc,
    float* __restrict__ alpha) {
  int v = (blockIdx.x * blockDim.x + threadIdx.x) >> 6;
  int lane = threadIdx.x & 63;
  if (v >= N_NODES) return;
  int begin = indptr[v], end = indptr[v + 1];
  float er_v = er[v];

  float m = -INFINITY;
  for (int j = begin + lane; j < end; j += 64) {
    float e = el[adjsrc[j]] + er_v;
    e = (e >= 0.f) ? e : NEG_SLOPE * e;
    alpha[j] = e;
    m = fmaxf(m, e);
  }
  m = waveReduceMax(m);

  float ss = 0.f;
  for (int j = begin + lane; j < end; j += 64) {
    float ex = __expf(alpha[j] - m);
    alpha[j] = ex;
    ss += ex;
  }
  float denom = waveReduceSum(ss);
  float inv = (end > begin) ? 1.f / denom : 0.f;

  for (int j = begin + lane; j < end; j += 64) alpha[j] *= inv;
}

// ========== XCD-sliced gather, slot-per-node (no cross-lane reduction) ==========
// slice = bid&7 -> XCD (2.56 MB table slice resident in that XCD's 4 MiB L2).
// lane = (slot, sub): slot owns one node, sub owns 8 cols (uint4) of the slice.
// Loop to max degree of the wave's 8 nodes; 4-deep unroll -> 4 independent
// gather chains in flight; masked tail (clamped addr, weight 0). All addresses
// are uniform_base + 32-bit voffset (saddr form). Each lane's result is stored
// directly (64 lanes x 16B = 1KB store), no reduction. Plain stores warm the
// next hop's L2 slice.
__global__ __launch_bounds__(256, 8) void gather_slc(
    const unsigned short* __restrict__ zin, const float* __restrict__ alpha,
    const int* __restrict__ indptr, const int* __restrict__ adjsrc,
    const float* __restrict__ bias, int self_term,
    unsigned short* __restrict__ out_bf, float* __restrict__ out_f32) {
  int slice = blockIdx.x & 7;
  int grp = blockIdx.x >> 3;                    // 0..624
  int wave = threadIdx.x >> 6, lane = threadIdx.x & 63;
  int slot = lane >> 3, sub = lane & 7;
  int v = grp * 32 + wave * 8 + slot;           // this lane's node
  unsigned cbyte = (unsigned)(slice * 128 + sub * 16);
  const char* zb = (const char*)zin;
  const char* ab = (const char*)adjsrc;
  const char* wb = (const char*)alpha;

  int b = indptr[v];
  unsigned ue = (unsigned)indptr[v + 1];
  int deg = (int)ue - b;
  int md = deg;                                  // max degree over the 8 slots
  md = max(md, __shfl_xor(md, 8, 64));
  md = max(md, __shfl_xor(md, 16, 64));
  md = max(md, __shfl_xor(md, 32, 64));

  float acc[8];
  if (self_term) {
    uint4 sz = *(const uint4*)(zb + (((unsigned)v) << 10) + cbyte);
    unpack8(sz, acc);
  } else {
#pragma unroll
    for (int i = 0; i < 8; ++i) acc[i] = 0.f;
  }

  unsigned jb = (unsigned)b;
  const unsigned EMAX = (unsigned)(N_EDGES - 1);
#pragma nounroll
  for (int t = 0; t < md; t += 4) {
    unsigned j0 = jb + (unsigned)t;
    unsigned a0 = min(j0 + 0u, EMAX) << 2;
    unsigned a1 = min(j0 + 1u, EMAX) << 2;
    unsigned a2 = min(j0 + 2u, EMAX) << 2;
    unsigned a3 = min(j0 + 3u, EMAX) << 2;
    int i0 = *(const int*)(ab + a0);
    int i1 = *(const int*)(ab + a1);
    int i2 = *(const int*)(ab + a2);
    int i3 = *(const int*)(ab + a3);
    float w0 = alpha ? *(const float*)(wb + a0) : 1.f;
    float w1 = alpha ? *(const float*)(wb + a1) : 1.f;
    float w2 = alpha ? *(const float*)(wb + a2) : 1.f;
    float w3 = alpha ? *(const float*)(wb + a3) : 1.f;
    w0 = (j0 + 0u < ue) ? w0 : 0.f;
    w1 = (j0 + 1u < ue) ? w1 : 0.f;
    w2 = (j0 + 2u < ue) ? w2 : 0.f;
    w3 = (j0 + 3u < ue) ? w3 : 0.f;
    uint4 z0 = *(const uint4*)(zb + (((unsigned)i0) << 10) + cbyte);
    uint4 z1 = *(const uint4*)(zb + (((unsigned)i1) << 10) + cbyte);
    uint4 z2 = *(const uint4*)(zb + (((unsigned)i2) << 10) + cbyte);
    uint4 z3 = *(const uint4*)(zb + (((unsigned)i3) << 10) + cbyte);
    float f0[8], f1[8], f2[8], f3[8];
    unpack8(z0, f0); unpack8(z1, f1); unpack8(z2, f2); unpack8(z3, f3);
#pragma unroll
    for (int i = 0; i < 8; ++i) {
      acc[i] = fmaf(w0, f0[i], acc[i]);
      acc[i] = fmaf(w1, f1[i], acc[i]);
      acc[i] = fmaf(w2, f2[i], acc[i]);
      acc[i] = fmaf(w3, f3[i], acc[i]);
    }
  }

  if (bias) {
    const float4* b4 = (const float4*)(bias + slice * 64 + sub * 8);
    float4 b0 = b4[0], b1 = b4[1];
    acc[0] += b0.x; acc[1] += b0.y; acc[2] += b0.z; acc[3] += b0.w;
    acc[4] += b1.x; acc[5] += b1.y; acc[6] += b1.z; acc[7] += b1.w;
  }
  if (out_bf) {
    uint4 pv = pack8(acc);
    *(uint4*)((char*)out_bf + (((unsigned)v) << 10) + cbyte) = pv;
  } else {
    char* p = (char*)out_f32 + (((unsigned)v) << 11) + cbyte * 2;
    *(f32x4*)p = (f32x4){acc[0], acc[1], acc[2], acc[3]};
    *(f32x4*)(p + 16) = (f32x4){acc[4], acc[5], acc[6], acc[7]};
  }
}

// ================= launch =================
extern "C" void kernel_launch(void* const* d_in, const int* in_sizes, int n_in,
                              void* d_out, int out_size, void* d_ws, size_t ws_size,
                              hipStream_t stream) {
  const float* feat = (const float*)d_in[0];
  const float* fc_W = (const float*)d_in[1];
  const float* fc_b = (const float*)d_in[2];
  const float* gat_W = (const float*)d_in[3];
  const float* gat_al = (const float*)d_in[4];
  const float* gat_ar = (const float*)d_in[5];
  const float* gat_b = (const float*)d_in[6];
  // d_in[7] = beta unused (reference returns Z_prev)
  const int* src = (const int*)d_in[8];
  const int* dst = (const int*)d_in[9];
  float* out = (float*)d_out;

  char* w = (char*)d_ws;
  auto alloc = [&](size_t bytes) {
    char* p = w;
    w += (bytes + 255) & ~(size_t)255;
    return p;
  };
  unsigned short* hbf   = (unsigned short*)alloc((size_t)M_PAD * DIM_H * 2);
  unsigned short* fcWt  = (unsigned short*)alloc((size_t)DIM_H * DIM_IN * 2);
  unsigned short* gatWt = (unsigned short*)alloc((size_t)NUM_GNNS * DIM_H * DIM_H * 2);
  float* el    = (float*)alloc((size_t)N_NODES * 4);
  float* er    = (float*)alloc((size_t)N_NODES * 4);
  int* counts  = (int*)alloc((size_t)2 * N_NODES * 4);   // counts+cursor contiguous
  int* cursor  = counts + N_NODES;
  int* indptr  = (int*)alloc((size_t)(N_NODES + 1) * 4);
  int* adjsrc  = (int*)alloc((size_t)N_EDGES * 4);
  char* uni = alloc((size_t)M_PAD * DIM_IN * 2);   // Abf (30.9 MB) -> alpha (1.28 MB) -> Z1 (20.6 MB)
  unsigned short* Abf = (unsigned short*)uni;      // live: convert + first GEMM only
  float* alpha = (float*)uni;                      // live: GAT layers only
  unsigned short* Z1  = (unsigned short*)uni;      // live: propagation only
  unsigned short* zbf = (unsigned short*)d_out;

  // ---- CSR build ----
  hipMemsetAsync(counts, 0, sizeof(int) * 2 * N_NODES, stream);
  count_edges<<<(N_EDGES + 255) / 256, 256, 0, stream>>>(dst, counts);
  scan_kernel<<<1, 1024, 0, stream>>>(counts, indptr);
  fill_adj<<<(N_EDGES + 255) / 256, 256, 0, stream>>>(src, dst, indptr, cursor, adjsrc);

  // ---- bf16 prep ----
  convert_feat<<<(M_PAD * DIM_IN / 8 + 255) / 256, 256, 0, stream>>>(feat, Abf);
  transpose_bf16<<<dim3(DIM_IN / 32, DIM_H / 32, 1), dim3(32, 8), 0, stream>>>(fc_W, fcWt, DIM_IN, DIM_H);
  transpose_bf16<<<dim3(DIM_H / 32, DIM_H / 32, NUM_GNNS), dim3(32, 8), 0, stream>>>(gat_W, gatWt, DIM_H, DIM_H);

  gemm_mfma_bf16<<<GEMM_GRID, 256, 0, stream>>>(Abf, fcWt, fc_b, hbf, DIM_IN);

  int nwaveblocks = (N_NODES * 64 + 255) / 256;
  for (int l = 0; l < NUM_GNNS; ++l) {
    gemm_mfma_bf16<<<GEMM_GRID, 256, 0, stream>>>(hbf, gatWt + (size_t)l * DIM_H * DIM_H,
                                                  nullptr, zbf, DIM_H);
    eler_bf<<<nwaveblocks, 256, 0, stream>>>(zbf, gat_al + (size_t)l * DIM_H,
                                             gat_ar + (size_t)l * DIM_H, el, er);
    edge_softmax_alpha<<<nwaveblocks, 256, 0, stream>>>(el, er, indptr, adjsrc, alpha);
    gather_slc<<<SLC_GRID, 256, 0, stream>>>(
        zbf, alpha, indptr, adjsrc, gat_b + (size_t)l * DIM_H, 0, hbf, nullptr);
  }

  // ---- 3 propagation hops (self term, weight 1) ----
  gather_slc<<<SLC_GRID, 256, 0, stream>>>(hbf, nullptr, indptr, adjsrc, nullptr, 1, Z1, nullptr);
  gather_slc<<<SLC_GRID, 256, 0, stream>>>(Z1, nullptr, indptr, adjsrc, nullptr, 1, hbf, nullptr);
  gather_slc<<<SLC_GRID, 256, 0, stream>>>(hbf, nullptr, indptr, adjsrc, nullptr, 1, nullptr, out);
}